// Round 9
// baseline (1000.384 us; speedup 1.0000x reference)
//
#include <hip/hip_runtime.h>

// ============================================================================
// DecoderGenerator: 2-layer LSTM decoder + additive attention + big vocab
// projection + NLL, fully fused on-device.
//
//   1. prep_kernel     : bf16-cast weights/enc, gather embeddings, transpose
//                        enc, init h-state buffers, zero flags.
//   2. a0_kernel       : A0 = xs @ W_ih0^T + b  (hoisted layer-0 input GEMM)
//   3. lstm_kernel     : persistent kernel, 256 WGs x 512 threads.
//                        WGs 0..31  : ROUND-6 LSTM loop; ROUND 14 isolated
//                                     change: split dependent MFMA chains
//                                     (L0: 2x8, L1: 4x8 independent accs).
//                        WGs 32..255: freeloaders — fcW f32->bf16, then
//                                     pe = enc@We^T + attn_b.
//   4. phpe_kernel     : ph = Hall@Wh^T only (z=1)
//   5. logits_kernel   : ROUND 14: 2 t-values per block (halves pe re-reads)
//   6. att_kernel      : softmax over b (axis=1 of (T,B,L) — per reference!)
//   7. weighted_kernel : weighted = att @ enc  (per-batch GEMM) -> G[:,512:]
//   8. fc_kernel       : XCD-swizzled 128x128xBK64 GEMM + fused (max,sumexp)
//                        partials; ROUND 14: tgt fused as blocks 4000..4511.
//   9. row_lse_kernel  : parallel logsumexp merge + fused masked-mean NLL
//                        (atomic gsum + last-block-done -> d_out[0])
// ============================================================================

#define DI __device__ __forceinline__

typedef __attribute__((ext_vector_type(8))) short short8;
typedef __attribute__((ext_vector_type(4))) float floatx4;
typedef unsigned long long ull;

#define TSEQ   128
#define VOCAB  32000
#define GDIM   2048   // 4*H
#define NROW   2048   // B*T
#define KFC    1024   // 2*H
#define HPAD   520    // LDS row stride for h staging (512 + 8 pad) — ROUND-1

// ---------------- small helpers ----------------
DI float bf2f(unsigned short u) {
    union { unsigned u; float f; } x; x.u = ((unsigned)u) << 16; return x.f;
}
DI unsigned short f2bf(float f) {   // RNE float -> bf16
    unsigned u = __float_as_uint(f);
    unsigned r = (u + 0x7FFF + ((u >> 16) & 1)) >> 16;
    return (unsigned short)r;
}
DI short8 ld8(const unsigned short* p) { return *(const short8*)p; }
DI floatx4 mfma16(short8 a, short8 b, floatx4 c) {
    return __builtin_amdgcn_mfma_f32_16x16x32_bf16(a, b, c, 0, 0, 0);
}
DI float sigm(float x) { return __builtin_amdgcn_rcpf(1.f + __expf(-x)); }
DI float tanh_f(float x) {
    float xc = fminf(8.f, fmaxf(-8.f, x));
    float e  = __expf(2.f * xc);
    return (e - 1.f) * __builtin_amdgcn_rcpf(e + 1.f);
}

// async global -> LDS, 16B per lane. LDS dest must be wave-uniform base;
// lane l writes base + l*16. Global src is per-lane.
#define GLD16(gsrc, ldst)                                                     \
    __builtin_amdgcn_global_load_lds(                                         \
        (const __attribute__((address_space(1))) unsigned int*)(gsrc),        \
        (__attribute__((address_space(3))) unsigned int*)(ldst), 16, 0, 0)

// fallback path: make the failure visible instead of faulting
__global__ void zero_out_kernel(float* out, int n) {
    int i = blockIdx.x * 64 + threadIdx.x;
    if (i < n) out[i] = 0.f;
}

// ============================================================================
// 1. prep kernel : segmented grid-stride over all conversion jobs
// ============================================================================
__global__ void prep_kernel(const int* X, const float* enc, const float* emb,
                            const float* Wih0, const float* Whh0,
                            const float* Wih1, const float* Whh1,
                            const float* attnW, const float* h0,
                            unsigned short* wih0b, unsigned short* whh0b,
                            unsigned short* wih1b, unsigned short* whh1b,
                            unsigned short* whb, unsigned short* web,
                            unsigned short* encb, unsigned short* enctb,
                            unsigned short* xsb,
                            unsigned short* h0buf, unsigned short* h1buf,
                            int* ctrl) {
    if (blockIdx.x == 0) {              // zero all 3072 flag ints
#pragma unroll
        for (int j = 0; j < 12; ++j) ctrl[threadIdx.x + 256 * j] = 0;
    }
    long i = (long)blockIdx.x * 256 + threadIdx.x;
    const long NW = 1048576;
    const long NA = 262144;            // 512x512 half of attn_W
    if (i < NW) { wih0b[i] = f2bf(Wih0[i]); return; } i -= NW;
    if (i < NW) { whh0b[i] = f2bf(Whh0[i]); return; } i -= NW;
    if (i < NW) { wih1b[i] = f2bf(Wih1[i]); return; } i -= NW;
    if (i < NW) { whh1b[i] = f2bf(Whh1[i]); return; } i -= NW;
    if (i < NA) { long k = i >> 9, h = i & 511; whb[i] = f2bf(attnW[k * 1024 + h]);       return; } i -= NA;
    if (i < NA) { long k = i >> 9, h = i & 511; web[i] = f2bf(attnW[k * 1024 + 512 + h]); return; } i -= NA;
    if (i < NW) { encb[i] = f2bf(enc[i]); return; } i -= NW;
    if (i < NW) {  // enc_t[b][h][l] = enc[b][l][h]
        long b = i >> 16, r = i & 65535, h = r >> 7, l = r & 127;
        enctb[i] = f2bf(enc[(b * 128 + l) * 512 + h]); return;
    } i -= NW;
    if (i < NW) {  // xs[t*16+b][e] = emb[X[b][t]][e]
        long m = i >> 9, e = i & 511, t = m >> 4, b = m & 15;
        int xi = X[b * 129 + t];
        xi = (xi < 0) ? 0 : ((xi >= VOCAB) ? VOCAB - 1 : xi);   // defensive
        xsb[i] = f2bf(emb[(long)xi * 512 + e]); return;
    } i -= NW;
    if (i < 16384) {  // h inits into parity-1 buffers
        long layer = i >> 13, r = i & 8191;
        unsigned short v = f2bf(h0[layer * 8192 + r]);
        if (layer == 0) h0buf[8192 + r] = v; else h1buf[8192 + r] = v;
    }
}

// ============================================================================
// shared 64x64 MFMA tile: C[m0..+63][n0..+63] += A(m,k) * B(n,k)^T
// ============================================================================
DI void gemm64_acc(const unsigned short* A, const unsigned short* Bw,
                   int m0, int n0, int lda, int ldb, int nkb, floatx4 acc[4]) {
    int tid = threadIdx.x;
    int wv = tid >> 6, ln = tid & 63;
    int colL = ln & 15, koff = (ln >> 4) * 8;
    const unsigned short* ar  = A  + (size_t)(m0 + wv * 16 + colL) * lda + koff;
    const unsigned short* br0 = Bw + (size_t)(n0 +  0 + colL) * ldb + koff;
    const unsigned short* br1 = Bw + (size_t)(n0 + 16 + colL) * ldb + koff;
    const unsigned short* br2 = Bw + (size_t)(n0 + 32 + colL) * ldb + koff;
    const unsigned short* br3 = Bw + (size_t)(n0 + 48 + colL) * ldb + koff;
    for (int kb = 0; kb < nkb; ++kb) {
        short8 af = ld8(ar + kb * 32);
        acc[0] = mfma16(af, ld8(br0 + kb * 32), acc[0]);
        acc[1] = mfma16(af, ld8(br1 + kb * 32), acc[1]);
        acc[2] = mfma16(af, ld8(br2 + kb * 32), acc[2]);
        acc[3] = mfma16(af, ld8(br3 + kb * 32), acc[3]);
    }
}

// 2. A0 = xs @ W_ih0^T + (b_ih0 + b_hh0), stored bf16 (bias folded)
__global__ void a0_kernel(const unsigned short* xs, const unsigned short* wih0b,
                          const float* bih0, const float* bhh0, unsigned short* A0b) {
    floatx4 acc[4] = {{0,0,0,0},{0,0,0,0},{0,0,0,0},{0,0,0,0}};
    int m0 = blockIdx.x * 64, n0 = blockIdx.y * 64;
    gemm64_acc(xs, wih0b, m0, n0, 512, 512, 16, acc);
    int tid = threadIdx.x, wv = tid >> 6, ln = tid & 63, colL = ln & 15, q = ln >> 4;
    int mrow = m0 + wv * 16;
#pragma unroll
    for (int nt = 0; nt < 4; ++nt) {
        int col = n0 + nt * 16 + colL;
        float bb = bih0[col] + bhh0[col];
#pragma unroll
        for (int r = 0; r < 4; ++r)
            A0b[(size_t)(mrow + q * 4 + r) * GDIM + col] = f2bf(acc[nt][r] + bb);
    }
}

// ============================================================================
// 3. persistent LSTM kernel.  256 WGs x 512 threads.
//    WGs 0..31: ROUND-6 LSTM structure; ROUND-14 isolated change: split
//    dependent MFMA chains (L0: 2x8, L1: 4x8 independent accumulators).
//    WGs 32..255: freeloaders — fcW f32->bf16, then pe = enc@We^T + attn_b.
// ============================================================================
__global__ __launch_bounds__(512, 1)
void lstm_kernel(const unsigned short* A0b,
                 const unsigned short* whh0b, const unsigned short* wih1b,
                 const unsigned short* whh1b,
                 const float* bih1, const float* bhh1, const float* c0in,
                 unsigned short* h0buf, unsigned short* h1buf,
                 unsigned short* Hall, unsigned short* Gmat, int* flags,
                 const float* fcW, unsigned short* fcWb,
                 const unsigned short* encb, const unsigned short* web,
                 const float* attnb, float* pe) {
    int wg = blockIdx.x;            // 0..255
    int tid = threadIdx.x;          // 0..511

    if (wg >= 32) {
        // -------- freeloader job 1: convert fcW while the LSTM runs --------
        {
            const float4* src = (const float4*)fcW;
            ushort4* dst = (ushort4*)fcWb;
            for (long i = (long)(wg - 32) * 512 + tid; i < 8192000; i += 224 * 512) {
                float4 v = src[i];
                ushort4 o;
                o.x = f2bf(v.x); o.y = f2bf(v.y); o.z = f2bf(v.z); o.w = f2bf(v.w);
                dst[i] = o;
            }
        }
        // -------- freeloader job 2: pe = enc@We^T + attn_b (64x64 tiles) ----
        {
            int g = tid >> 8, lt = tid & 255;
            int slot = (wg - 32) * 2 + g;
            if (slot < 256) {
                int m0 = (slot >> 3) * 64, n0 = (slot & 7) * 64;
                int wv = lt >> 6, ln = lt & 63;
                int colL = ln & 15, q = ln >> 4, koff = q * 8;
                floatx4 acc[4] = {{0,0,0,0},{0,0,0,0},{0,0,0,0},{0,0,0,0}};
                const unsigned short* ar  = encb + (size_t)(m0 + wv * 16 + colL) * 512 + koff;
                const unsigned short* br0 = web  + (size_t)(n0 +  0 + colL) * 512 + koff;
                const unsigned short* br1 = web  + (size_t)(n0 + 16 + colL) * 512 + koff;
                const unsigned short* br2 = web  + (size_t)(n0 + 32 + colL) * 512 + koff;
                const unsigned short* br3 = web  + (size_t)(n0 + 48 + colL) * 512 + koff;
                for (int kb = 0; kb < 16; ++kb) {
                    short8 af = ld8(ar + kb * 32);
                    acc[0] = mfma16(af, ld8(br0 + kb * 32), acc[0]);
                    acc[1] = mfma16(af, ld8(br1 + kb * 32), acc[1]);
                    acc[2] = mfma16(af, ld8(br2 + kb * 32), acc[2]);
                    acc[3] = mfma16(af, ld8(br3 + kb * 32), acc[3]);
                }
                int mrow = m0 + wv * 16;
#pragma unroll
                for (int nt = 0; nt < 4; ++nt) {
                    int col = n0 + nt * 16 + colL;
                    float bb = attnb[col];
#pragma unroll
                    for (int r = 0; r < 4; ++r)
                        pe[(size_t)(mrow + q * 4 + r) * 512 + col] = acc[nt][r] + bb;
                }
            }
        }
        return;
    }

    __shared__ unsigned short hsh0[16 * HPAD];   // h0[t-1], shared by both halves
    __shared__ unsigned short hsh1[16 * HPAD];   // h1[t-2], L1 half only
    __shared__ float gbuf[2][4][16][16];         // [half][gate][batch][unit]
    int half = tid >> 8;            // 0 = L0, 1 = L1
    int lt   = tid & 255;
    int wv = lt >> 6, ln = lt & 63;
    int u0 = wg * 16;
    int n0 = wv * 512 + u0;         // gate column base (wave-of-half = gate)
    int colL = ln & 15, q = ln >> 4, koff = q * 8;
    int eb = lt >> 4, eu = lt & 15; // elementwise mapping within half
    float c = c0in[half * 8192 + eb * 512 + u0 + eu];
    float bias1 = (half == 1) ? (bih1[n0 + colL] + bhh1[n0 + colL]) : 0.f;

    // ---- one-time: weight slices into registers (128 VGPRs) ----
    short8 wA[16], wB[16];
    if (half == 0) {
        const unsigned short* wr0 = whh0b + (size_t)(n0 + colL) * 512 + koff;
#pragma unroll
        for (int kb = 0; kb < 16; ++kb) wA[kb] = ld8(wr0 + kb * 32);
#pragma unroll
        for (int kb = 0; kb < 16; ++kb) wB[kb] = wA[kb];   // unused, keep defined
    } else {
        const unsigned short* wr1 = wih1b + (size_t)(n0 + colL) * 512 + koff;
        const unsigned short* wr2 = whh1b + (size_t)(n0 + colL) * 512 + koff;
#pragma unroll
        for (int kb = 0; kb < 16; ++kb) wA[kb] = ld8(wr1 + kb * 32);
#pragma unroll
        for (int kb = 0; kb < 16; ++kb) wB[kb] = ld8(wr2 + kb * 32);
    }

    // A0 prefetch for tick 0 (L0 half)
    floatx4 a0pre = {0, 0, 0, 0};
    if (half == 0) {
        const unsigned short* a0r = A0b + (size_t)0 * GDIM + n0 + colL;
        a0pre[0] = bf2f(a0r[(q * 4 + 0) * GDIM]);
        a0pre[1] = bf2f(a0r[(q * 4 + 1) * GDIM]);
        a0pre[2] = bf2f(a0r[(q * 4 + 2) * GDIM]);
        a0pre[3] = bf2f(a0r[(q * 4 + 3) * GDIM]);
    }

    // staging geometry: flat = tid*16 over [16][512]: row = tid>>5,
    // col = (tid&31)*16. 32B/thread.
    int srow = tid >> 5;
    int scol = (tid & 31) << 4;
    unsigned long long* d0 = (unsigned long long*)&hsh0[srow * HPAD + scol];
    unsigned long long* d1 = (unsigned long long*)&hsh1[srow * HPAD + scol];

#pragma unroll 1
    for (int t = 0; t <= TSEQ; ++t) {
        bool actL0 = (t < TSEQ);
        bool actL1 = (t >= 1);
        // ---- stage h vectors LLC -> LDS (relaxed agent atomics, 16KB each) ----
        {
            const unsigned long long* s0 =
                (const unsigned long long*)(h0buf + ((t - 1) & 1) * 8192) + (size_t)tid * 4;
            unsigned long long v0 = __hip_atomic_load(s0 + 0, __ATOMIC_RELAXED, __HIP_MEMORY_SCOPE_AGENT);
            unsigned long long v1 = __hip_atomic_load(s0 + 1, __ATOMIC_RELAXED, __HIP_MEMORY_SCOPE_AGENT);
            unsigned long long v2 = __hip_atomic_load(s0 + 2, __ATOMIC_RELAXED, __HIP_MEMORY_SCOPE_AGENT);
            unsigned long long v3 = __hip_atomic_load(s0 + 3, __ATOMIC_RELAXED, __HIP_MEMORY_SCOPE_AGENT);
            if (actL1) {
                const unsigned long long* s1 =
                    (const unsigned long long*)(h1buf + ((t - 2) & 1) * 8192) + (size_t)tid * 4;
                unsigned long long w0 = __hip_atomic_load(s1 + 0, __ATOMIC_RELAXED, __HIP_MEMORY_SCOPE_AGENT);
                unsigned long long w1 = __hip_atomic_load(s1 + 1, __ATOMIC_RELAXED, __HIP_MEMORY_SCOPE_AGENT);
                unsigned long long w2 = __hip_atomic_load(s1 + 2, __ATOMIC_RELAXED, __HIP_MEMORY_SCOPE_AGENT);
                unsigned long long w3 = __hip_atomic_load(s1 + 3, __ATOMIC_RELAXED, __HIP_MEMORY_SCOPE_AGENT);
                d0[0] = v0; d0[1] = v1; d0[2] = v2; d0[3] = v3;
                d1[0] = w0; d1[1] = w1; d1[2] = w2; d1[3] = w3;
            } else {
                d0[0] = v0; d0[1] = v1; d0[2] = v2; d0[3] = v3;
            }
        }
        __syncthreads();
        // ---- MFMA: LDS fragments x register weights (SPLIT CHAINS) ----
        bool act = half ? actL1 : actL0;
        if (act) {
            floatx4 acc;
            const unsigned short* hl0 = hsh0 + colL * HPAD + koff;
            if (half == 0) {
                floatx4 c0v = a0pre, c1v = {0, 0, 0, 0};
#pragma unroll
                for (int kb = 0; kb < 8; ++kb) {
                    c0v = mfma16(ld8(hl0 + (2 * kb) * 32),     wA[2 * kb],     c0v);
                    c1v = mfma16(ld8(hl0 + (2 * kb + 1) * 32), wA[2 * kb + 1], c1v);
                }
                acc = c0v + c1v;
            } else {
                const unsigned short* hl1 = hsh1 + colL * HPAD + koff;
                floatx4 a0c = {bias1, bias1, bias1, bias1};
                floatx4 a1c = {0, 0, 0, 0}, b0c = {0, 0, 0, 0}, b1c = {0, 0, 0, 0};
#pragma unroll
                for (int kb = 0; kb < 8; ++kb) {
                    a0c = mfma16(ld8(hl0 + (2 * kb) * 32),     wA[2 * kb],     a0c);
                    a1c = mfma16(ld8(hl0 + (2 * kb + 1) * 32), wA[2 * kb + 1], a1c);
                    b0c = mfma16(ld8(hl1 + (2 * kb) * 32),     wB[2 * kb],     b0c);
                    b1c = mfma16(ld8(hl1 + (2 * kb + 1) * 32), wB[2 * kb + 1], b1c);
                }
                acc = (a0c + a1c) + (b0c + b1c);
            }
            // D layout: row = batch = q*4+r, col = unit = colL
            gbuf[half][wv][q * 4 + 0][colL] = acc[0];
            gbuf[half][wv][q * 4 + 1][colL] = acc[1];
            gbuf[half][wv][q * 4 + 2][colL] = acc[2];
            gbuf[half][wv][q * 4 + 3][colL] = acc[3];
        }
        __syncthreads();
        if (act) {
            float gi = gbuf[half][0][eb][eu], gf = gbuf[half][1][eb][eu];
            float gg = gbuf[half][2][eb][eu], go = gbuf[half][3][eb][eu];
            float c2 = sigm(gf) * c + sigm(gi) * tanh_f(gg);
            float h2 = sigm(go) * tanh_f(c2);
            c = c2;
            unsigned hb = (unsigned)f2bf(h2);
            unsigned up = __shfl_down(hb, 1, 64);
            unsigned packed = hb | (up << 16);
            if ((eu & 1) == 0) {
                if (half == 0) {
                    __hip_atomic_store(
                        (unsigned*)(h0buf + (t & 1) * 8192 + eb * 512 + u0 + eu),
                        packed, __ATOMIC_RELAXED, __HIP_MEMORY_SCOPE_AGENT);
                } else {
                    int s = t - 1;
                    __hip_atomic_store(
                        (unsigned*)(h1buf + (s & 1) * 8192 + eb * 512 + u0 + eu),
                        packed, __ATOMIC_RELAXED, __HIP_MEMORY_SCOPE_AGENT);
                    *(unsigned*)&Hall[(size_t)(s * 16 + eb) * 512 + u0 + eu] = packed;
                    *(unsigned*)&Gmat[(size_t)(eb * 128 + s) * KFC + u0 + eu] = packed;
                }
            }
        }
        if (t < TSEQ) {
            // publish: __syncthreads drains all waves' vmem (hipcc emits
            // s_waitcnt vmcnt(0) before s_barrier) -> h-stores LLC-visible.
            __syncthreads();
            if (tid == 0)
                __hip_atomic_store(flags + wg * 32, t + 1,
                                   __ATOMIC_RELAXED, __HIP_MEMORY_SCOPE_AGENT);
            // prefetch next tick's A0 now — stays in flight to its use.
            if (half == 0 && t + 1 < TSEQ) {
                const unsigned short* a0r = A0b + (size_t)((t + 1) * 16) * GDIM + n0 + colL;
                a0pre[0] = bf2f(a0r[(q * 4 + 0) * GDIM]);
                a0pre[1] = bf2f(a0r[(q * 4 + 1) * GDIM]);
                a0pre[2] = bf2f(a0r[(q * 4 + 2) * GDIM]);
                a0pre[3] = bf2f(a0r[(q * 4 + 3) * GDIM]);
            }
            // ALL threads poll. Thread tid polls WG (tid&31) — exactly the
            // producer of the chunk it stages next iteration.
            {
                int* f = flags + (tid & 31) * 32;
                int g = 0;
                while (__hip_atomic_load(f, __ATOMIC_RELAXED,
                                         __HIP_MEMORY_SCOPE_AGENT) < t + 1) {
                    __builtin_amdgcn_s_sleep(1);
                    if (++g > (1 << 22)) break;   // fail loud, not hung
                }
                asm volatile("" ::: "memory");    // no load hoisting past poll
            }
        }
    }
}

// 4. ph = Hall @ Wh^T   (pe computed by lstm freeloaders)
__global__ void phpe_kernel(const unsigned short* Hall, const unsigned short* encb,
                            const unsigned short* whb, const unsigned short* web,
                            const float* attnb, float* ph, float* pe) {
    bool ispe = (blockIdx.z != 0);
    const unsigned short* A  = ispe ? encb : Hall;
    const unsigned short* Bw = ispe ? web  : whb;
    float* out = ispe ? pe : ph;
    floatx4 acc[4] = {{0,0,0,0},{0,0,0,0},{0,0,0,0},{0,0,0,0}};
    int m0 = blockIdx.x * 64, n0 = blockIdx.y * 64;
    gemm64_acc(A, Bw, m0, n0, 512, 512, 16, acc);
    int tid = threadIdx.x, wv = tid >> 6, ln = tid & 63, colL = ln & 15, q = ln >> 4;
    int mrow = m0 + wv * 16;
#pragma unroll
    for (int nt = 0; nt < 4; ++nt) {
        int col = n0 + nt * 16 + colL;
        float bb = ispe ? attnb[col] : 0.f;
#pragma unroll
        for (int r = 0; r < 4; ++r)
            out[(size_t)(mrow + q * 4 + r) * 512 + col] = acc[nt][r] + bb;
    }
}

// 5. logits: 2 t-values per block (grid 1024 x 256). Halves pe re-reads.
//    logits[t][l][b] = sum_k v_w[k] * tanh(ph[t*16+b][k] + pe[b*128+l][k])
__global__ void logits_kernel(const float* ph, const float* pe, const float* vw,
                              float* logits) {
    int qb = blockIdx.x;            // 0..1023
    int b = qb & 15, tp = qb >> 4;  // tp 0..63
    int t0 = tp * 2, t1 = t0 + 1;
    int tid = threadIdx.x, wv = tid >> 6, ln = tid & 63;
    const float* ph0r = ph + (size_t)(t0 * 16 + b) * 512 + ln * 8;
    const float* ph1r = ph + (size_t)(t1 * 16 + b) * 512 + ln * 8;
    floatx4 pa0 = *(const floatx4*)ph0r;
    floatx4 pa1 = *(const floatx4*)(ph0r + 4);
    floatx4 pb0 = *(const floatx4*)ph1r;
    floatx4 pb1 = *(const floatx4*)(ph1r + 4);
    const float* vwr = vw + ln * 8;
    floatx4 vw0 = *(const floatx4*)vwr;
    floatx4 vw1 = *(const floatx4*)(vwr + 4);
    for (int li = 0; li < 32; ++li) {
        int ll = wv * 32 + li;
        const float* per = pe + (size_t)(b * 128 + ll) * 512 + ln * 8;
        floatx4 p0 = *(const floatx4*)per;
        floatx4 p1 = *(const floatx4*)(per + 4);
        float s0 = 0.f, s1 = 0.f;
#pragma unroll
        for (int j = 0; j < 4; ++j) {
            s0 += vw0[j] * tanh_f(pa0[j] + p0[j]);
            s1 += vw0[j] * tanh_f(pb0[j] + p0[j]);
        }
#pragma unroll
        for (int j = 0; j < 4; ++j) {
            s0 += vw1[j] * tanh_f(pa1[j] + p1[j]);
            s1 += vw1[j] * tanh_f(pb1[j] + p1[j]);
        }
#pragma unroll
        for (int off = 32; off; off >>= 1) {
            s0 += __shfl_xor(s0, off, 64);
            s1 += __shfl_xor(s1, off, 64);
        }
        if (ln == 0) {
            logits[((size_t)t0 * 128 + ll) * 16 + b] = s0;
            logits[((size_t)t1 * 128 + ll) * 16 + b] = s1;
        }
    }
}

// 6. softmax over b (axis=1 of (T,B,L)) -> att_bf16[b][t][l]
__global__ void att_kernel(const float* logits, unsigned short* attb) {
    int t = blockIdx.x, l = threadIdx.x;     // 128 threads
    const float* p = logits + ((size_t)t * 128 + l) * 16;
    float x[16], mx = -1e30f;
#pragma unroll
    for (int j = 0; j < 16; ++j) { x[j] = p[j]; mx = fmaxf(mx, x[j]); }
    float s = 0.f;
#pragma unroll
    for (int j = 0; j < 16; ++j) { x[j] = __expf(x[j] - mx); s += x[j]; }
    float inv = __builtin_amdgcn_rcpf(s);
#pragma unroll
    for (int j = 0; j < 16; ++j)
        attb[((size_t)j * 128 + t) * 128 + l] = f2bf(x[j] * inv);
}

// 7. weighted[b][t][h] = att[b] @ enc[b]  ->  G[b*128+t][512+h]
__global__ void weighted_kernel(const unsigned short* attb, const unsigned short* enctb,
                                unsigned short* Gmat) {
    int b = blockIdx.z;
    floatx4 acc[4] = {{0,0,0,0},{0,0,0,0},{0,0,0,0},{0,0,0,0}};
    int m0 = blockIdx.x * 64, n0 = blockIdx.y * 64;
    gemm64_acc(attb + (size_t)b * 128 * 128, enctb + (size_t)b * 512 * 128,
               m0, n0, 128, 128, 4, acc);
    int tid = threadIdx.x, wv = tid >> 6, ln = tid & 63, colL = ln & 15, q = ln >> 4;
    int mrow = m0 + wv * 16;
#pragma unroll
    for (int nt = 0; nt < 4; ++nt) {
        int col = n0 + nt * 16 + colL;
#pragma unroll
        for (int r = 0; r < 4; ++r)
            Gmat[(size_t)(b * 128 + mrow + q * 4 + r) * KFC + 512 + col] = f2bf(acc[nt][r]);
    }
}

// ============================================================================
// 8. fc GEMM (XCD-swizzled) + fused per-row (max, sumexp) partials.
//    Blocks 0..3999: GEMM. Blocks 4000..4511: tgt (target logits).
// ============================================================================
__global__ __launch_bounds__(256)
void fc_kernel(const unsigned short* G, const unsigned short* fcWb,
               const float* fcb, float2* partials,
               const int* X, const float* fcWf, float* tgt) {
    __shared__ __align__(16) unsigned short lA[128 * 64];
    __shared__ __align__(16) unsigned short lB[128 * 64];
    __shared__ float2 pbuf[128][2];
    int tid = threadIdx.x;

    if (blockIdx.x >= 4000) {
        // ---- fused tgt: z_y = G[r] . fc_W[y] + fc_b[y] ----
        int r = (blockIdx.x - 4000) * 4 + (tid >> 6);
        int ln = tid & 63;
        int b = r >> 7, t = r & 127;
        int y = X[b * 129 + t + 1];
        y = (y < 0) ? 0 : ((y >= VOCAB) ? VOCAB - 1 : y);   // defensive
        const unsigned short* g = G + (size_t)r * KFC;
        const float* w = fcWf + (size_t)y * KFC;
        float s = 0.f;
        for (int j = ln; j < KFC; j += 64) s += bf2f(g[j]) * w[j];
#pragma unroll
        for (int off = 32; off; off >>= 1) s += __shfl_xor(s, off, 64);
        if (ln == 0) tgt[r] = s + fcb[y];
        return;
    }

    int orig = blockIdx.x;               // 0..3999
    int wgid = (orig & 7) * 500 + (orig >> 3);   // XCD-chunked, bijective
    int mwg = wgid & 15;                 // 16 M-tiles (fast within XCD)
    int nwg = wgid >> 4;                 // 250 N-tiles
    int n_base = nwg * 128, m_base = mwg * 128;
    int wv = tid >> 6, l = tid & 63;
    int wr = wv >> 1, wc = wv & 1;
    int colL = l & 15, q16 = l >> 4, koff = q16 * 8;
    int srow = l >> 3, scol = (l & 7) * 8;     // staging sub-pattern per chunk

    floatx4 acc[4][4];
#pragma unroll
    for (int i = 0; i < 4; ++i)
#pragma unroll
        for (int j = 0; j < 4; ++j) acc[i][j] = (floatx4){0, 0, 0, 0};

    const unsigned short* gA = G    + (size_t)m_base * KFC;
    const unsigned short* gB = fcWb + (size_t)n_base * KFC;

    for (int kt = 0; kt < 16; ++kt) {
        if (kt) __syncthreads();     // previous tile's reads done before overwrite
        int k0 = kt * 64;
#pragma unroll
        for (int j = 0; j < 4; ++j) {
            int c = wv * 4 + j;
            const unsigned short* ga = gA + (size_t)(c * 8 + srow) * KFC + k0 + scol;
            const unsigned short* gb = gB + (size_t)(c * 8 + srow) * KFC + k0 + scol;
            GLD16(ga, lA + c * 512);
            GLD16(gb, lB + c * 512);
        }
        __syncthreads();             // barrier drains vmcnt -> tiles resident
#pragma unroll
        for (int ks = 0; ks < 2; ++ks) {
            const unsigned short* ap = lA + (wr * 64 + colL) * 64 + ks * 32 + koff;
            const unsigned short* bp = lB + (wc * 64 + colL) * 64 + ks * 32 + koff;
            short8 aF[4], bF[4];
#pragma unroll
            for (int ma = 0; ma < 4; ++ma) aF[ma] = ld8(ap + ma * 16 * 64);
#pragma unroll
            for (int nb = 0; nb < 4; ++nb) bF[nb] = ld8(bp + nb * 16 * 64);
#pragma unroll
            for (int ma = 0; ma < 4; ++ma)
#pragma unroll
                for (int nb = 0; nb < 4; ++nb)
                    acc[ma][nb] = mfma16(aF[ma], bF[nb], acc[ma][nb]);
        }
    }

    // ---- epilogue: per-row (max, sumexp) over this WG's 128 cols ----
    float cb[4];
#pragma unroll
    for (int nb = 0; nb < 4; ++nb)
        cb[nb] = fcb[n_base + wc * 64 + nb * 16 + colL];

#pragma unroll
    for (int ma = 0; ma < 4; ++ma) {
#pragma unroll
        for (int r = 0; r < 4; ++r) {
            float v0 = acc[ma][0][r] + cb[0];
            float v1 = acc[ma][1][r] + cb[1];
            float v2 = acc[ma][2][r] + cb[2];
            float v3 = acc[ma][3][r] + cb[3];
            float M = fmaxf(fmaxf(v0, v1), fmaxf(v2, v3));
#pragma unroll
            for (int off = 1; off < 16; off <<= 1) M = fmaxf(M, __shfl_xor(M, off, 64));
            float e = __expf(v0 - M) + __expf(v1 - M) + __expf(v2 - M) + __expf(v3 - M);
#pragma unroll
            for (int off = 1; off < 16; off <<= 1) e += __shfl_xor(e, off, 64);
            if (colL == 0)
                pbuf[wr * 64 + ma * 16 + q16 * 4 + r][wc] = make_float2(M, e);
        }
    }
    __syncthreads();
    if (tid < 128) {    // merge the two col-halves, write global partial
        float2 a = pbuf[tid][0], b = pbuf[tid][1];
        float M = fmaxf(a.x, b.x);
        float S = a.y * __expf(a.x - M) + b.y * __expf(b.x - M);
        partials[(size_t)(m_base + tid) * 250 + nwg] = make_float2(M, S);
    }
}

// ============================================================================
// 9. row_lse + fused finalize: 256 blocks x 256 thr, 8 rows/block (32 lanes
//    per row merge 250 partials), then per-block masked (lse - tgt) sums are
//    atomically accumulated; the LAST block writes out[0] = vs/vc.
//    gctl: [0]=vs (float), [1]=vc (float), [2]=done counter (int). Zeroed by
//    prep (part of the 3072-int ctrl region).
// ============================================================================
__global__ void row_lse_kernel(const float2* partials, const float* tgt,
                               const int* X, float* out, int* gctl) {
    __shared__ float svb[8], scb[8];
    int g = threadIdx.x >> 5;                        // 0..7
    int row = blockIdx.x * 8 + g;
    int ln = threadIdx.x & 31;
    const float2* p = partials + (size_t)row * 250;
    float M = -1e30f, S = 0.f;
    for (int i = ln; i < 250; i += 32) {
        float2 q = p[i];
        float nm = fmaxf(M, q.x);
        S = S * __expf(M - nm) + q.y * __expf(q.x - nm);
        M = nm;
    }
#pragma unroll
    for (int off = 16; off; off >>= 1) {
        float Mo = __shfl_xor(M, off, 64);
        float So = __shfl_xor(S, off, 64);
        float nm = fmaxf(M, Mo);
        S = S * __expf(M - nm) + So * __expf(Mo - nm);
        M = nm;
    }
    if (ln == 0) {
        float lse = M + __logf(S);
        int b = row >> 7, t = row & 127;
        int y = X[b * 129 + t + 1];
        svb[g] = (y != 0) ? (lse - tgt[row]) : 0.f;
        scb[g] = (y != 0) ? 1.f : 0.f;
    }
    __syncthreads();
    if (threadIdx.x == 0) {
        float vs = 0.f, vc = 0.f;
#pragma unroll
        for (int j = 0; j < 8; ++j) { vs += svb[j]; vc += scb[j]; }
        float* gsum = (float*)gctl;
        atomicAdd(&gsum[0], vs);
        atomicAdd(&gsum[1], vc);
        __threadfence();
        int done = atomicAdd(&gctl[2], 1);
        if (done == 255) {            // last block: all adds are LLC-visible
            __threadfence();
            float fvs = __hip_atomic_load(&gsum[0], __ATOMIC_RELAXED,
                                          __HIP_MEMORY_SCOPE_AGENT);
            float fvc = __hip_atomic_load(&gsum[1], __ATOMIC_RELAXED,
                                          __HIP_MEMORY_SCOPE_AGENT);
            out[0] = fvs / fvc;
        }
    }
}

// ============================================================================
// launcher
// ============================================================================
extern "C" void kernel_launch(void* const* d_in, const int* in_sizes, int n_in,
                              void* d_out, int out_size, void* d_ws, size_t ws_size,
                              hipStream_t stream) {
    const int*   X     = (const int*)d_in[0];
    const float* enc   = (const float*)d_in[2];
    const float* emb   = (const float*)d_in[3];
    const float* Wih0  = (const float*)d_in[4];
    const float* Whh0  = (const float*)d_in[5];
    const float* bih0  = (const float*)d_in[6];
    const float* bhh0  = (const float*)d_in[7];
    const float* Wih1  = (const float*)d_in[8];
    const float* Whh1  = (const float*)d_in[9];
    const float* bih1  = (const float*)d_in[10];
    const float* bhh1  = (const float*)d_in[11];
    const float* attnW = (const float*)d_in[12];
    const float* attnb = (const float*)d_in[13];
    const float* vw    = (const float*)d_in[14];
    const float* fcW   = (const float*)d_in[15];
    const float* fcb   = (const float*)d_in[16];
    const float* h0    = (const float*)d_in[17];
    const float* c0    = (const float*)d_in[18];

    char* ws = (char*)d_ws;
    size_t off = 0;
    auto take = [&](size_t bytes) { char* p = ws + off; off += (bytes + 255) & ~(size_t)255; return p; };
    int*            ctrl    = (int*)           take(12288);
    unsigned short* wih0b   = (unsigned short*)take(2097152);
    unsigned short* whh0b   = (unsigned short*)take(2097152);
    unsigned short* wih1b   = (unsigned short*)take(2097152);
    unsigned short* whh1b   = (unsigned short*)take(2097152);
    unsigned short* whb     = (unsigned short*)take(524288);
    unsigned short* web     = (unsigned short*)take(524288);
    unsigned short* encb    = (unsigned short*)take(2097152);
    unsigned short* enctb   = (unsigned short*)take(2097152);
    unsigned short* xsb     = (unsigned short*)take(2097152);
    unsigned short* h0buf   = (unsigned short*)take(32768);
    unsigned short* h1buf   = (unsigned short*)take(32768);
    unsigned short* A0b     = (unsigned short*)take(8388608);
    unsigned short* hallb   = (unsigned short*)take(2097152);
    unsigned short* gmat    = (unsigned short*)take(4194304);
    float*          ph      = (float*)         take(4194304);
    float*          pe      = (float*)         take(4194304);
    float*          logitsb = (float*)         take(1048576);
    unsigned short* attb    = (unsigned short*)take(524288);
    float2*         parts   = (float2*)        take(4096000);
    float*          tgt     = (float*)         take(8192);
    unsigned short* fcWb    = (unsigned short*)take(65536000);
    size_t need = off;
    (void)in_sizes; (void)n_in;

    if (ws_size < need) {
        // Not enough scratch: fail visibly (absmax error) instead of faulting.
        hipLaunchKernelGGL(zero_out_kernel, dim3((out_size + 63) / 64), dim3(64),
                           0, stream, (float*)d_out, out_size);
        return;
    }

    hipLaunchKernelGGL(prep_kernel, dim3(30784), dim3(256), 0, stream,
                       X, enc, emb, Wih0, Whh0, Wih1, Whh1, attnW, h0,
                       wih0b, whh0b, wih1b, whh1b, whb, web, encb, enctb,
                       xsb, h0buf, h1buf, ctrl);
    hipLaunchKernelGGL(a0_kernel, dim3(32, 32), dim3(256), 0, stream,
                       xsb, wih0b, bih0, bhh0, A0b);
    hipLaunchKernelGGL(lstm_kernel, dim3(256), dim3(512), 0, stream,
                       A0b, whh0b, wih1b, whh1b, bih1, bhh1, c0,
                       h0buf, h1buf, hallb, gmat, ctrl, fcW, fcWb,
                       encb, web, attnb, pe);
    hipLaunchKernelGGL(phpe_kernel, dim3(32, 8, 1), dim3(256), 0, stream,
                       hallb, encb, whb, web, attnb, ph, pe);
    hipLaunchKernelGGL(logits_kernel, dim3(1024), dim3(256), 0, stream,
                       ph, pe, vw, logitsb);
    hipLaunchKernelGGL(att_kernel, dim3(128), dim3(128), 0, stream,
                       logitsb, attb);
    hipLaunchKernelGGL(weighted_kernel, dim3(2, 8, 16), dim3(256), 0, stream,
                       attb, enctb, gmat);
    hipLaunchKernelGGL(fc_kernel, dim3(4512), dim3(256), 0, stream,
                       gmat, fcWb, fcb, parts, X, fcW, tgt);
    hipLaunchKernelGGL(row_lse_kernel, dim3(256), dim3(256), 0, stream,
                       parts, tgt, X, (float*)d_out, ctrl + 2048);
}

// Round 10
// 981.777 us; speedup vs baseline: 1.0190x; 1.0190x over previous
//
#include <hip/hip_runtime.h>

// ============================================================================
// DecoderGenerator: 2-layer LSTM decoder + additive attention + big vocab
// projection + NLL, fully fused on-device.
//
//   1. prep_kernel     : bf16-cast weights/enc, gather embeddings, transpose
//                        enc, init h-state buffers, zero flags.
//   2. a0_kernel       : A0 = xs @ W_ih0^T + b  (hoisted layer-0 input GEMM)
//   3. lstm_kernel     : persistent kernel, 256 WGs x 512 threads.
//                        WGs 0..31  : ROUND-6 LSTM + split MFMA chains;
//                                     ROUND 15: Hall/Gmat stores DEFERRED
//                                     past the publish (only the h1buf ack
//                                     remains on the per-tick drain path).
//                        WGs 32..255: freeloaders — fcW f32->bf16, then
//                                     pe = enc@We^T + attn_b.
//   4. phpe_kernel     : ph = Hall@Wh^T only (z=1)
//   5. logits_kernel   : ROUND 15: reverted to 1 t per block (grid 2048) —
//                        the 2-t variant cost occupancy (round-8 regression).
//   6. att_kernel      : softmax over b (axis=1 of (T,B,L) — per reference!)
//   7. weighted_kernel : weighted = att @ enc  (per-batch GEMM) -> G[:,512:]
//   8. fc_kernel       : XCD-swizzled 128x128xBK64 GEMM + fused (max,sumexp)
//                        partials; tgt fused as blocks 4000..4511.
//   9. row_lse_kernel  : parallel logsumexp merge + fused masked-mean NLL
//                        (atomic gsum + last-block-done -> d_out[0])
// ============================================================================

#define DI __device__ __forceinline__

typedef __attribute__((ext_vector_type(8))) short short8;
typedef __attribute__((ext_vector_type(4))) float floatx4;
typedef unsigned long long ull;

#define TSEQ   128
#define VOCAB  32000
#define GDIM   2048   // 4*H
#define NROW   2048   // B*T
#define KFC    1024   // 2*H
#define HPAD   520    // LDS row stride for h staging (512 + 8 pad) — ROUND-1

// ---------------- small helpers ----------------
DI float bf2f(unsigned short u) {
    union { unsigned u; float f; } x; x.u = ((unsigned)u) << 16; return x.f;
}
DI unsigned short f2bf(float f) {   // RNE float -> bf16
    unsigned u = __float_as_uint(f);
    unsigned r = (u + 0x7FFF + ((u >> 16) & 1)) >> 16;
    return (unsigned short)r;
}
DI short8 ld8(const unsigned short* p) { return *(const short8*)p; }
DI floatx4 mfma16(short8 a, short8 b, floatx4 c) {
    return __builtin_amdgcn_mfma_f32_16x16x32_bf16(a, b, c, 0, 0, 0);
}
DI float sigm(float x) { return __builtin_amdgcn_rcpf(1.f + __expf(-x)); }
DI float tanh_f(float x) {
    float xc = fminf(8.f, fmaxf(-8.f, x));
    float e  = __expf(2.f * xc);
    return (e - 1.f) * __builtin_amdgcn_rcpf(e + 1.f);
}

// async global -> LDS, 16B per lane. LDS dest must be wave-uniform base;
// lane l writes base + l*16. Global src is per-lane.
#define GLD16(gsrc, ldst)                                                     \
    __builtin_amdgcn_global_load_lds(                                         \
        (const __attribute__((address_space(1))) unsigned int*)(gsrc),        \
        (__attribute__((address_space(3))) unsigned int*)(ldst), 16, 0, 0)

// fallback path: make the failure visible instead of faulting
__global__ void zero_out_kernel(float* out, int n) {
    int i = blockIdx.x * 64 + threadIdx.x;
    if (i < n) out[i] = 0.f;
}

// ============================================================================
// 1. prep kernel : segmented grid-stride over all conversion jobs
// ============================================================================
__global__ void prep_kernel(const int* X, const float* enc, const float* emb,
                            const float* Wih0, const float* Whh0,
                            const float* Wih1, const float* Whh1,
                            const float* attnW, const float* h0,
                            unsigned short* wih0b, unsigned short* whh0b,
                            unsigned short* wih1b, unsigned short* whh1b,
                            unsigned short* whb, unsigned short* web,
                            unsigned short* encb, unsigned short* enctb,
                            unsigned short* xsb,
                            unsigned short* h0buf, unsigned short* h1buf,
                            int* ctrl) {
    if (blockIdx.x == 0) {              // zero all 3072 flag ints
#pragma unroll
        for (int j = 0; j < 12; ++j) ctrl[threadIdx.x + 256 * j] = 0;
    }
    long i = (long)blockIdx.x * 256 + threadIdx.x;
    const long NW = 1048576;
    const long NA = 262144;            // 512x512 half of attn_W
    if (i < NW) { wih0b[i] = f2bf(Wih0[i]); return; } i -= NW;
    if (i < NW) { whh0b[i] = f2bf(Whh0[i]); return; } i -= NW;
    if (i < NW) { wih1b[i] = f2bf(Wih1[i]); return; } i -= NW;
    if (i < NW) { whh1b[i] = f2bf(Whh1[i]); return; } i -= NW;
    if (i < NA) { long k = i >> 9, h = i & 511; whb[i] = f2bf(attnW[k * 1024 + h]);       return; } i -= NA;
    if (i < NA) { long k = i >> 9, h = i & 511; web[i] = f2bf(attnW[k * 1024 + 512 + h]); return; } i -= NA;
    if (i < NW) { encb[i] = f2bf(enc[i]); return; } i -= NW;
    if (i < NW) {  // enc_t[b][h][l] = enc[b][l][h]
        long b = i >> 16, r = i & 65535, h = r >> 7, l = r & 127;
        enctb[i] = f2bf(enc[(b * 128 + l) * 512 + h]); return;
    } i -= NW;
    if (i < NW) {  // xs[t*16+b][e] = emb[X[b][t]][e]
        long m = i >> 9, e = i & 511, t = m >> 4, b = m & 15;
        int xi = X[b * 129 + t];
        xi = (xi < 0) ? 0 : ((xi >= VOCAB) ? VOCAB - 1 : xi);   // defensive
        xsb[i] = f2bf(emb[(long)xi * 512 + e]); return;
    } i -= NW;
    if (i < 16384) {  // h inits into parity-1 buffers
        long layer = i >> 13, r = i & 8191;
        unsigned short v = f2bf(h0[layer * 8192 + r]);
        if (layer == 0) h0buf[8192 + r] = v; else h1buf[8192 + r] = v;
    }
}

// ============================================================================
// shared 64x64 MFMA tile: C[m0..+63][n0..+63] += A(m,k) * B(n,k)^T
// ============================================================================
DI void gemm64_acc(const unsigned short* A, const unsigned short* Bw,
                   int m0, int n0, int lda, int ldb, int nkb, floatx4 acc[4]) {
    int tid = threadIdx.x;
    int wv = tid >> 6, ln = tid & 63;
    int colL = ln & 15, koff = (ln >> 4) * 8;
    const unsigned short* ar  = A  + (size_t)(m0 + wv * 16 + colL) * lda + koff;
    const unsigned short* br0 = Bw + (size_t)(n0 +  0 + colL) * ldb + koff;
    const unsigned short* br1 = Bw + (size_t)(n0 + 16 + colL) * ldb + koff;
    const unsigned short* br2 = Bw + (size_t)(n0 + 32 + colL) * ldb + koff;
    const unsigned short* br3 = Bw + (size_t)(n0 + 48 + colL) * ldb + koff;
    for (int kb = 0; kb < nkb; ++kb) {
        short8 af = ld8(ar + kb * 32);
        acc[0] = mfma16(af, ld8(br0 + kb * 32), acc[0]);
        acc[1] = mfma16(af, ld8(br1 + kb * 32), acc[1]);
        acc[2] = mfma16(af, ld8(br2 + kb * 32), acc[2]);
        acc[3] = mfma16(af, ld8(br3 + kb * 32), acc[3]);
    }
}

// 2. A0 = xs @ W_ih0^T + (b_ih0 + b_hh0), stored bf16 (bias folded)
__global__ void a0_kernel(const unsigned short* xs, const unsigned short* wih0b,
                          const float* bih0, const float* bhh0, unsigned short* A0b) {
    floatx4 acc[4] = {{0,0,0,0},{0,0,0,0},{0,0,0,0},{0,0,0,0}};
    int m0 = blockIdx.x * 64, n0 = blockIdx.y * 64;
    gemm64_acc(xs, wih0b, m0, n0, 512, 512, 16, acc);
    int tid = threadIdx.x, wv = tid >> 6, ln = tid & 63, colL = ln & 15, q = ln >> 4;
    int mrow = m0 + wv * 16;
#pragma unroll
    for (int nt = 0; nt < 4; ++nt) {
        int col = n0 + nt * 16 + colL;
        float bb = bih0[col] + bhh0[col];
#pragma unroll
        for (int r = 0; r < 4; ++r)
            A0b[(size_t)(mrow + q * 4 + r) * GDIM + col] = f2bf(acc[nt][r] + bb);
    }
}

// ============================================================================
// 3. persistent LSTM kernel.  256 WGs x 512 threads.
//    WGs 0..31: ROUND-6 LSTM + split chains; ROUND-15: Hall/Gmat stores
//    deferred past the publish point (issued during the poll window, drained
//    at the NEXT tick's barrier when their acks are long since returned).
//    WGs 32..255: freeloaders — fcW f32->bf16, then pe = enc@We^T + attn_b.
// ============================================================================
__global__ __launch_bounds__(512, 1)
void lstm_kernel(const unsigned short* A0b,
                 const unsigned short* whh0b, const unsigned short* wih1b,
                 const unsigned short* whh1b,
                 const float* bih1, const float* bhh1, const float* c0in,
                 unsigned short* h0buf, unsigned short* h1buf,
                 unsigned short* Hall, unsigned short* Gmat, int* flags,
                 const float* fcW, unsigned short* fcWb,
                 const unsigned short* encb, const unsigned short* web,
                 const float* attnb, float* pe) {
    int wg = blockIdx.x;            // 0..255
    int tid = threadIdx.x;          // 0..511

    if (wg >= 32) {
        // -------- freeloader job 1: convert fcW while the LSTM runs --------
        {
            const float4* src = (const float4*)fcW;
            ushort4* dst = (ushort4*)fcWb;
            for (long i = (long)(wg - 32) * 512 + tid; i < 8192000; i += 224 * 512) {
                float4 v = src[i];
                ushort4 o;
                o.x = f2bf(v.x); o.y = f2bf(v.y); o.z = f2bf(v.z); o.w = f2bf(v.w);
                dst[i] = o;
            }
        }
        // -------- freeloader job 2: pe = enc@We^T + attn_b (64x64 tiles) ----
        {
            int g = tid >> 8, lt = tid & 255;
            int slot = (wg - 32) * 2 + g;
            if (slot < 256) {
                int m0 = (slot >> 3) * 64, n0 = (slot & 7) * 64;
                int wv = lt >> 6, ln = lt & 63;
                int colL = ln & 15, q = ln >> 4, koff = q * 8;
                floatx4 acc[4] = {{0,0,0,0},{0,0,0,0},{0,0,0,0},{0,0,0,0}};
                const unsigned short* ar  = encb + (size_t)(m0 + wv * 16 + colL) * 512 + koff;
                const unsigned short* br0 = web  + (size_t)(n0 +  0 + colL) * 512 + koff;
                const unsigned short* br1 = web  + (size_t)(n0 + 16 + colL) * 512 + koff;
                const unsigned short* br2 = web  + (size_t)(n0 + 32 + colL) * 512 + koff;
                const unsigned short* br3 = web  + (size_t)(n0 + 48 + colL) * 512 + koff;
                for (int kb = 0; kb < 16; ++kb) {
                    short8 af = ld8(ar + kb * 32);
                    acc[0] = mfma16(af, ld8(br0 + kb * 32), acc[0]);
                    acc[1] = mfma16(af, ld8(br1 + kb * 32), acc[1]);
                    acc[2] = mfma16(af, ld8(br2 + kb * 32), acc[2]);
                    acc[3] = mfma16(af, ld8(br3 + kb * 32), acc[3]);
                }
                int mrow = m0 + wv * 16;
#pragma unroll
                for (int nt = 0; nt < 4; ++nt) {
                    int col = n0 + nt * 16 + colL;
                    float bb = attnb[col];
#pragma unroll
                    for (int r = 0; r < 4; ++r)
                        pe[(size_t)(mrow + q * 4 + r) * 512 + col] = acc[nt][r] + bb;
                }
            }
        }
        return;
    }

    __shared__ unsigned short hsh0[16 * HPAD];   // h0[t-1], shared by both halves
    __shared__ unsigned short hsh1[16 * HPAD];   // h1[t-2], L1 half only
    __shared__ float gbuf[2][4][16][16];         // [half][gate][batch][unit]
    int half = tid >> 8;            // 0 = L0, 1 = L1
    int lt   = tid & 255;
    int wv = lt >> 6, ln = lt & 63;
    int u0 = wg * 16;
    int n0 = wv * 512 + u0;         // gate column base (wave-of-half = gate)
    int colL = ln & 15, q = ln >> 4, koff = q * 8;
    int eb = lt >> 4, eu = lt & 15; // elementwise mapping within half
    float c = c0in[half * 8192 + eb * 512 + u0 + eu];
    float bias1 = (half == 1) ? (bih1[n0 + colL] + bhh1[n0 + colL]) : 0.f;

    // ---- one-time: weight slices into registers (128 VGPRs) ----
    short8 wA[16], wB[16];
    if (half == 0) {
        const unsigned short* wr0 = whh0b + (size_t)(n0 + colL) * 512 + koff;
#pragma unroll
        for (int kb = 0; kb < 16; ++kb) wA[kb] = ld8(wr0 + kb * 32);
#pragma unroll
        for (int kb = 0; kb < 16; ++kb) wB[kb] = wA[kb];   // unused, keep defined
    } else {
        const unsigned short* wr1 = wih1b + (size_t)(n0 + colL) * 512 + koff;
        const unsigned short* wr2 = whh1b + (size_t)(n0 + colL) * 512 + koff;
#pragma unroll
        for (int kb = 0; kb < 16; ++kb) wA[kb] = ld8(wr1 + kb * 32);
#pragma unroll
        for (int kb = 0; kb < 16; ++kb) wB[kb] = ld8(wr2 + kb * 32);
    }

    // A0 prefetch for tick 0 (L0 half)
    floatx4 a0pre = {0, 0, 0, 0};
    if (half == 0) {
        const unsigned short* a0r = A0b + (size_t)0 * GDIM + n0 + colL;
        a0pre[0] = bf2f(a0r[(q * 4 + 0) * GDIM]);
        a0pre[1] = bf2f(a0r[(q * 4 + 1) * GDIM]);
        a0pre[2] = bf2f(a0r[(q * 4 + 2) * GDIM]);
        a0pre[3] = bf2f(a0r[(q * 4 + 3) * GDIM]);
    }

    // staging geometry: flat = tid*16 over [16][512]: row = tid>>5,
    // col = (tid&31)*16. 32B/thread.
    int srow = tid >> 5;
    int scol = (tid & 31) << 4;
    unsigned long long* d0 = (unsigned long long*)&hsh0[srow * HPAD + scol];
    unsigned long long* d1 = (unsigned long long*)&hsh1[srow * HPAD + scol];

#pragma unroll 1
    for (int t = 0; t <= TSEQ; ++t) {
        bool actL0 = (t < TSEQ);
        bool actL1 = (t >= 1);
        // ---- stage h vectors LLC -> LDS (relaxed agent atomics, 16KB each) ----
        {
            const unsigned long long* s0 =
                (const unsigned long long*)(h0buf + ((t - 1) & 1) * 8192) + (size_t)tid * 4;
            unsigned long long v0 = __hip_atomic_load(s0 + 0, __ATOMIC_RELAXED, __HIP_MEMORY_SCOPE_AGENT);
            unsigned long long v1 = __hip_atomic_load(s0 + 1, __ATOMIC_RELAXED, __HIP_MEMORY_SCOPE_AGENT);
            unsigned long long v2 = __hip_atomic_load(s0 + 2, __ATOMIC_RELAXED, __HIP_MEMORY_SCOPE_AGENT);
            unsigned long long v3 = __hip_atomic_load(s0 + 3, __ATOMIC_RELAXED, __HIP_MEMORY_SCOPE_AGENT);
            if (actL1) {
                const unsigned long long* s1 =
                    (const unsigned long long*)(h1buf + ((t - 2) & 1) * 8192) + (size_t)tid * 4;
                unsigned long long w0 = __hip_atomic_load(s1 + 0, __ATOMIC_RELAXED, __HIP_MEMORY_SCOPE_AGENT);
                unsigned long long w1 = __hip_atomic_load(s1 + 1, __ATOMIC_RELAXED, __HIP_MEMORY_SCOPE_AGENT);
                unsigned long long w2 = __hip_atomic_load(s1 + 2, __ATOMIC_RELAXED, __HIP_MEMORY_SCOPE_AGENT);
                unsigned long long w3 = __hip_atomic_load(s1 + 3, __ATOMIC_RELAXED, __HIP_MEMORY_SCOPE_AGENT);
                d0[0] = v0; d0[1] = v1; d0[2] = v2; d0[3] = v3;
                d1[0] = w0; d1[1] = w1; d1[2] = w2; d1[3] = w3;
            } else {
                d0[0] = v0; d0[1] = v1; d0[2] = v2; d0[3] = v3;
            }
        }
        __syncthreads();
        // ---- MFMA: LDS fragments x register weights (split chains) ----
        bool act = half ? actL1 : actL0;
        if (act) {
            floatx4 acc;
            const unsigned short* hl0 = hsh0 + colL * HPAD + koff;
            if (half == 0) {
                floatx4 c0v = a0pre, c1v = {0, 0, 0, 0};
#pragma unroll
                for (int kb = 0; kb < 8; ++kb) {
                    c0v = mfma16(ld8(hl0 + (2 * kb) * 32),     wA[2 * kb],     c0v);
                    c1v = mfma16(ld8(hl0 + (2 * kb + 1) * 32), wA[2 * kb + 1], c1v);
                }
                acc = c0v + c1v;
            } else {
                const unsigned short* hl1 = hsh1 + colL * HPAD + koff;
                floatx4 a0c = {bias1, bias1, bias1, bias1};
                floatx4 a1c = {0, 0, 0, 0}, b0c = {0, 0, 0, 0}, b1c = {0, 0, 0, 0};
#pragma unroll
                for (int kb = 0; kb < 8; ++kb) {
                    a0c = mfma16(ld8(hl0 + (2 * kb) * 32),     wA[2 * kb],     a0c);
                    a1c = mfma16(ld8(hl0 + (2 * kb + 1) * 32), wA[2 * kb + 1], a1c);
                    b0c = mfma16(ld8(hl1 + (2 * kb) * 32),     wB[2 * kb],     b0c);
                    b1c = mfma16(ld8(hl1 + (2 * kb + 1) * 32), wB[2 * kb + 1], b1c);
                }
                acc = (a0c + a1c) + (b0c + b1c);
            }
            // D layout: row = batch = q*4+r, col = unit = colL
            gbuf[half][wv][q * 4 + 0][colL] = acc[0];
            gbuf[half][wv][q * 4 + 1][colL] = acc[1];
            gbuf[half][wv][q * 4 + 2][colL] = acc[2];
            gbuf[half][wv][q * 4 + 3][colL] = acc[3];
        }
        __syncthreads();
        unsigned packed = 0;
        if (act) {
            float gi = gbuf[half][0][eb][eu], gf = gbuf[half][1][eb][eu];
            float gg = gbuf[half][2][eb][eu], go = gbuf[half][3][eb][eu];
            float c2 = sigm(gf) * c + sigm(gi) * tanh_f(gg);
            float h2 = sigm(go) * tanh_f(c2);
            c = c2;
            unsigned hb = (unsigned)f2bf(h2);
            unsigned up = __shfl_down(hb, 1, 64);
            packed = hb | (up << 16);
            if ((eu & 1) == 0) {
                if (half == 0) {
                    __hip_atomic_store(
                        (unsigned*)(h0buf + (t & 1) * 8192 + eb * 512 + u0 + eu),
                        packed, __ATOMIC_RELAXED, __HIP_MEMORY_SCOPE_AGENT);
                } else {
                    int s = t - 1;
                    __hip_atomic_store(
                        (unsigned*)(h1buf + (s & 1) * 8192 + eb * 512 + u0 + eu),
                        packed, __ATOMIC_RELAXED, __HIP_MEMORY_SCOPE_AGENT);
                    // Hall/Gmat stores DEFERRED past the publish barrier.
                }
            }
        }
        if (t < TSEQ) {
            // publish: __syncthreads drains all waves' vmem (hipcc emits
            // s_waitcnt vmcnt(0) before s_barrier) -> h-stores LLC-visible.
            // Only 1 store-ack (h0buf/h1buf) is on this drain now.
            __syncthreads();
            if (tid == 0)
                __hip_atomic_store(flags + wg * 32, t + 1,
                                   __ATOMIC_RELAXED, __HIP_MEMORY_SCOPE_AGENT);
            // prefetch next tick's A0 — stays in flight to its use.
            if (half == 0 && t + 1 < TSEQ) {
                const unsigned short* a0r = A0b + (size_t)((t + 1) * 16) * GDIM + n0 + colL;
                a0pre[0] = bf2f(a0r[(q * 4 + 0) * GDIM]);
                a0pre[1] = bf2f(a0r[(q * 4 + 1) * GDIM]);
                a0pre[2] = bf2f(a0r[(q * 4 + 2) * GDIM]);
                a0pre[3] = bf2f(a0r[(q * 4 + 3) * GDIM]);
            }
            // deferred Hall/Gmat stores for this tick's h1 (s = t-1): issued
            // in the poll window; drained at NEXT tick's barrier, by which
            // time their acks are long returned (off the critical path).
            if (half == 1 && t >= 1 && (eu & 1) == 0) {
                int s = t - 1;
                *(unsigned*)&Hall[(size_t)(s * 16 + eb) * 512 + u0 + eu] = packed;
                *(unsigned*)&Gmat[(size_t)(eb * 128 + s) * KFC + u0 + eu] = packed;
            }
            // ALL threads poll. Thread tid polls WG (tid&31) — exactly the
            // producer of the chunk it stages next iteration.
            {
                int* f = flags + (tid & 31) * 32;
                int g = 0;
                while (__hip_atomic_load(f, __ATOMIC_RELAXED,
                                         __HIP_MEMORY_SCOPE_AGENT) < t + 1) {
                    __builtin_amdgcn_s_sleep(1);
                    if (++g > (1 << 22)) break;   // fail loud, not hung
                }
                asm volatile("" ::: "memory");    // no load hoisting past poll
            }
        } else if (half == 1 && (eu & 1) == 0) {
            // final tick (t == TSEQ): deferred stores for s = 127
            int s = t - 1;
            *(unsigned*)&Hall[(size_t)(s * 16 + eb) * 512 + u0 + eu] = packed;
            *(unsigned*)&Gmat[(size_t)(eb * 128 + s) * KFC + u0 + eu] = packed;
        }
    }
}

// 4. ph = Hall @ Wh^T   (pe computed by lstm freeloaders)
__global__ void phpe_kernel(const unsigned short* Hall, const unsigned short* encb,
                            const unsigned short* whb, const unsigned short* web,
                            const float* attnb, float* ph, float* pe) {
    bool ispe = (blockIdx.z != 0);
    const unsigned short* A  = ispe ? encb : Hall;
    const unsigned short* Bw = ispe ? web  : whb;
    float* out = ispe ? pe : ph;
    floatx4 acc[4] = {{0,0,0,0},{0,0,0,0},{0,0,0,0},{0,0,0,0}};
    int m0 = blockIdx.x * 64, n0 = blockIdx.y * 64;
    gemm64_acc(A, Bw, m0, n0, 512, 512, 16, acc);
    int tid = threadIdx.x, wv = tid >> 6, ln = tid & 63, colL = ln & 15, q = ln >> 4;
    int mrow = m0 + wv * 16;
#pragma unroll
    for (int nt = 0; nt < 4; ++nt) {
        int col = n0 + nt * 16 + colL;
        float bb = ispe ? attnb[col] : 0.f;
#pragma unroll
        for (int r = 0; r < 4; ++r)
            out[(size_t)(mrow + q * 4 + r) * 512 + col] = acc[nt][r] + bb;
    }
}

// 5. logits[t][l][b] = sum_k v_w[k] * tanh(ph[t*16+b][k] + pe[b*128+l][k])
//    (1 t per block, grid 2048 — reverted from the round-8 2-t variant)
__global__ void logits_kernel(const float* ph, const float* pe, const float* vw,
                              float* logits) {
    int m = blockIdx.x;             // t*16+b
    int t = m >> 4, b = m & 15;
    int tid = threadIdx.x, wv = tid >> 6, ln = tid & 63;
    const float* phr = ph + (size_t)m * 512 + ln * 8;
    floatx4 ph0 = *(const floatx4*)phr;
    floatx4 ph1 = *(const floatx4*)(phr + 4);
    const float* vwr = vw + ln * 8;
    floatx4 vw0 = *(const floatx4*)vwr;
    floatx4 vw1 = *(const floatx4*)(vwr + 4);
    for (int li = 0; li < 32; ++li) {
        int ll = wv * 32 + li;
        const float* per = pe + (size_t)(b * 128 + ll) * 512 + ln * 8;
        floatx4 p0 = *(const floatx4*)per;
        floatx4 p1 = *(const floatx4*)(per + 4);
        float s = 0.f;
#pragma unroll
        for (int j = 0; j < 4; ++j) s += vw0[j] * tanh_f(ph0[j] + p0[j]);
#pragma unroll
        for (int j = 0; j < 4; ++j) s += vw1[j] * tanh_f(ph1[j] + p1[j]);
#pragma unroll
        for (int off = 32; off; off >>= 1) s += __shfl_xor(s, off, 64);
        if (ln == 0) logits[((size_t)t * 128 + ll) * 16 + b] = s;
    }
}

// 6. softmax over b (axis=1 of (T,B,L)) -> att_bf16[b][t][l]
__global__ void att_kernel(const float* logits, unsigned short* attb) {
    int t = blockIdx.x, l = threadIdx.x;     // 128 threads
    const float* p = logits + ((size_t)t * 128 + l) * 16;
    float x[16], mx = -1e30f;
#pragma unroll
    for (int j = 0; j < 16; ++j) { x[j] = p[j]; mx = fmaxf(mx, x[j]); }
    float s = 0.f;
#pragma unroll
    for (int j = 0; j < 16; ++j) { x[j] = __expf(x[j] - mx); s += x[j]; }
    float inv = __builtin_amdgcn_rcpf(s);
#pragma unroll
    for (int j = 0; j < 16; ++j)
        attb[((size_t)j * 128 + t) * 128 + l] = f2bf(x[j] * inv);
}

// 7. weighted[b][t][h] = att[b] @ enc[b]  ->  G[b*128+t][512+h]
__global__ void weighted_kernel(const unsigned short* attb, const unsigned short* enctb,
                                unsigned short* Gmat) {
    int b = blockIdx.z;
    floatx4 acc[4] = {{0,0,0,0},{0,0,0,0},{0,0,0,0},{0,0,0,0}};
    int m0 = blockIdx.x * 64, n0 = blockIdx.y * 64;
    gemm64_acc(attb + (size_t)b * 128 * 128, enctb + (size_t)b * 512 * 128,
               m0, n0, 128, 128, 4, acc);
    int tid = threadIdx.x, wv = tid >> 6, ln = tid & 63, colL = ln & 15, q = ln >> 4;
    int mrow = m0 + wv * 16;
#pragma unroll
    for (int nt = 0; nt < 4; ++nt) {
        int col = n0 + nt * 16 + colL;
#pragma unroll
        for (int r = 0; r < 4; ++r)
            Gmat[(size_t)(b * 128 + mrow + q * 4 + r) * KFC + 512 + col] = f2bf(acc[nt][r]);
    }
}

// ============================================================================
// 8. fc GEMM (XCD-swizzled) + fused per-row (max, sumexp) partials.
//    Blocks 0..3999: GEMM. Blocks 4000..4511: tgt (target logits).
// ============================================================================
__global__ __launch_bounds__(256)
void fc_kernel(const unsigned short* G, const unsigned short* fcWb,
               const float* fcb, float2* partials,
               const int* X, const float* fcWf, float* tgt) {
    __shared__ __align__(16) unsigned short lA[128 * 64];
    __shared__ __align__(16) unsigned short lB[128 * 64];
    __shared__ float2 pbuf[128][2];
    int tid = threadIdx.x;

    if (blockIdx.x >= 4000) {
        // ---- fused tgt: z_y = G[r] . fc_W[y] + fc_b[y] ----
        int r = (blockIdx.x - 4000) * 4 + (tid >> 6);
        int ln = tid & 63;
        int b = r >> 7, t = r & 127;
        int y = X[b * 129 + t + 1];
        y = (y < 0) ? 0 : ((y >= VOCAB) ? VOCAB - 1 : y);   // defensive
        const unsigned short* g = G + (size_t)r * KFC;
        const float* w = fcWf + (size_t)y * KFC;
        float s = 0.f;
        for (int j = ln; j < KFC; j += 64) s += bf2f(g[j]) * w[j];
#pragma unroll
        for (int off = 32; off; off >>= 1) s += __shfl_xor(s, off, 64);
        if (ln == 0) tgt[r] = s + fcb[y];
        return;
    }

    int orig = blockIdx.x;               // 0..3999
    int wgid = (orig & 7) * 500 + (orig >> 3);   // XCD-chunked, bijective
    int mwg = wgid & 15;                 // 16 M-tiles (fast within XCD)
    int nwg = wgid >> 4;                 // 250 N-tiles
    int n_base = nwg * 128, m_base = mwg * 128;
    int wv = tid >> 6, l = tid & 63;
    int wr = wv >> 1, wc = wv & 1;
    int colL = l & 15, q16 = l >> 4, koff = q16 * 8;
    int srow = l >> 3, scol = (l & 7) * 8;     // staging sub-pattern per chunk

    floatx4 acc[4][4];
#pragma unroll
    for (int i = 0; i < 4; ++i)
#pragma unroll
        for (int j = 0; j < 4; ++j) acc[i][j] = (floatx4){0, 0, 0, 0};

    const unsigned short* gA = G    + (size_t)m_base * KFC;
    const unsigned short* gB = fcWb + (size_t)n_base * KFC;

    for (int kt = 0; kt < 16; ++kt) {
        if (kt) __syncthreads();     // previous tile's reads done before overwrite
        int k0 = kt * 64;
#pragma unroll
        for (int j = 0; j < 4; ++j) {
            int c = wv * 4 + j;
            const unsigned short* ga = gA + (size_t)(c * 8 + srow) * KFC + k0 + scol;
            const unsigned short* gb = gB + (size_t)(c * 8 + srow) * KFC + k0 + scol;
            GLD16(ga, lA + c * 512);
            GLD16(gb, lB + c * 512);
        }
        __syncthreads();             // barrier drains vmcnt -> tiles resident
#pragma unroll
        for (int ks = 0; ks < 2; ++ks) {
            const unsigned short* ap = lA + (wr * 64 + colL) * 64 + ks * 32 + koff;
            const unsigned short* bp = lB + (wc * 64 + colL) * 64 + ks * 32 + koff;
            short8 aF[4], bF[4];
#pragma unroll
            for (int ma = 0; ma < 4; ++ma) aF[ma] = ld8(ap + ma * 16 * 64);
#pragma unroll
            for (int nb = 0; nb < 4; ++nb) bF[nb] = ld8(bp + nb * 16 * 64);
#pragma unroll
            for (int ma = 0; ma < 4; ++ma)
#pragma unroll
                for (int nb = 0; nb < 4; ++nb)
                    acc[ma][nb] = mfma16(aF[ma], bF[nb], acc[ma][nb]);
        }
    }

    // ---- epilogue: per-row (max, sumexp) over this WG's 128 cols ----
    float cb[4];
#pragma unroll
    for (int nb = 0; nb < 4; ++nb)
        cb[nb] = fcb[n_base + wc * 64 + nb * 16 + colL];

#pragma unroll
    for (int ma = 0; ma < 4; ++ma) {
#pragma unroll
        for (int r = 0; r < 4; ++r) {
            float v0 = acc[ma][0][r] + cb[0];
            float v1 = acc[ma][1][r] + cb[1];
            float v2 = acc[ma][2][r] + cb[2];
            float v3 = acc[ma][3][r] + cb[3];
            float M = fmaxf(fmaxf(v0, v1), fmaxf(v2, v3));
#pragma unroll
            for (int off = 1; off < 16; off <<= 1) M = fmaxf(M, __shfl_xor(M, off, 64));
            float e = __expf(v0 - M) + __expf(v1 - M) + __expf(v2 - M) + __expf(v3 - M);
#pragma unroll
            for (int off = 1; off < 16; off <<= 1) e += __shfl_xor(e, off, 64);
            if (colL == 0)
                pbuf[wr * 64 + ma * 16 + q16 * 4 + r][wc] = make_float2(M, e);
        }
    }
    __syncthreads();
    if (tid < 128) {    // merge the two col-halves, write global partial
        float2 a = pbuf[tid][0], b = pbuf[tid][1];
        float M = fmaxf(a.x, b.x);
        float S = a.y * __expf(a.x - M) + b.y * __expf(b.x - M);
        partials[(size_t)(m_base + tid) * 250 + nwg] = make_float2(M, S);
    }
}

// ============================================================================
// 9. row_lse + fused finalize: 256 blocks x 256 thr, 8 rows/block (32 lanes
//    per row merge 250 partials), then per-block masked (lse - tgt) sums are
//    atomically accumulated; the LAST block writes out[0] = vs/vc.
//    gctl: [0]=vs (float), [1]=vc (float), [2]=done counter (int). Zeroed by
//    prep (part of the 3072-int ctrl region).
// ============================================================================
__global__ void row_lse_kernel(const float2* partials, const float* tgt,
                               const int* X, float* out, int* gctl) {
    __shared__ float svb[8], scb[8];
    int g = threadIdx.x >> 5;                        // 0..7
    int row = blockIdx.x * 8 + g;
    int ln = threadIdx.x & 31;
    const float2* p = partials + (size_t)row * 250;
    float M = -1e30f, S = 0.f;
    for (int i = ln; i < 250; i += 32) {
        float2 q = p[i];
        float nm = fmaxf(M, q.x);
        S = S * __expf(M - nm) + q.y * __expf(q.x - nm);
        M = nm;
    }
#pragma unroll
    for (int off = 16; off; off >>= 1) {
        float Mo = __shfl_xor(M, off, 64);
        float So = __shfl_xor(S, off, 64);
        float nm = fmaxf(M, Mo);
        S = S * __expf(M - nm) + So * __expf(Mo - nm);
        M = nm;
    }
    if (ln == 0) {
        float lse = M + __logf(S);
        int b = row >> 7, t = row & 127;
        int y = X[b * 129 + t + 1];
        svb[g] = (y != 0) ? (lse - tgt[row]) : 0.f;
        scb[g] = (y != 0) ? 1.f : 0.f;
    }
    __syncthreads();
    if (threadIdx.x == 0) {
        float vs = 0.f, vc = 0.f;
#pragma unroll
        for (int j = 0; j < 8; ++j) { vs += svb[j]; vc += scb[j]; }
        float* gsum = (float*)gctl;
        atomicAdd(&gsum[0], vs);
        atomicAdd(&gsum[1], vc);
        __threadfence();
        int done = atomicAdd(&gctl[2], 1);
        if (done == 255) {            // last block: all adds are LLC-visible
            __threadfence();
            float fvs = __hip_atomic_load(&gsum[0], __ATOMIC_RELAXED,
                                          __HIP_MEMORY_SCOPE_AGENT);
            float fvc = __hip_atomic_load(&gsum[1], __ATOMIC_RELAXED,
                                          __HIP_MEMORY_SCOPE_AGENT);
            out[0] = fvs / fvc;
        }
    }
}

// ============================================================================
// launcher
// ============================================================================
extern "C" void kernel_launch(void* const* d_in, const int* in_sizes, int n_in,
                              void* d_out, int out_size, void* d_ws, size_t ws_size,
                              hipStream_t stream) {
    const int*   X     = (const int*)d_in[0];
    const float* enc   = (const float*)d_in[2];
    const float* emb   = (const float*)d_in[3];
    const float* Wih0  = (const float*)d_in[4];
    const float* Whh0  = (const float*)d_in[5];
    const float* bih0  = (const float*)d_in[6];
    const float* bhh0  = (const float*)d_in[7];
    const float* Wih1  = (const float*)d_in[8];
    const float* Whh1  = (const float*)d_in[9];
    const float* bih1  = (const float*)d_in[10];
    const float* bhh1  = (const float*)d_in[11];
    const float* attnW = (const float*)d_in[12];
    const float* attnb = (const float*)d_in[13];
    const float* vw    = (const float*)d_in[14];
    const float* fcW   = (const float*)d_in[15];
    const float* fcb   = (const float*)d_in[16];
    const float* h0    = (const float*)d_in[17];
    const float* c0    = (const float*)d_in[18];

    char* ws = (char*)d_ws;
    size_t off = 0;
    auto take = [&](size_t bytes) { char* p = ws + off; off += (bytes + 255) & ~(size_t)255; return p; };
    int*            ctrl    = (int*)           take(12288);
    unsigned short* wih0b   = (unsigned short*)take(2097152);
    unsigned short* whh0b   = (unsigned short*)take(2097152);
    unsigned short* wih1b   = (unsigned short*)take(2097152);
    unsigned short* whh1b   = (unsigned short*)take(2097152);
    unsigned short* whb     = (unsigned short*)take(524288);
    unsigned short* web     = (unsigned short*)take(524288);
    unsigned short* encb    = (unsigned short*)take(2097152);
    unsigned short* enctb   = (unsigned short*)take(2097152);
    unsigned short* xsb     = (unsigned short*)take(2097152);
    unsigned short* h0buf   = (unsigned short*)take(32768);
    unsigned short* h1buf   = (unsigned short*)take(32768);
    unsigned short* A0b     = (unsigned short*)take(8388608);
    unsigned short* hallb   = (unsigned short*)take(2097152);
    unsigned short* gmat    = (unsigned short*)take(4194304);
    float*          ph      = (float*)         take(4194304);
    float*          pe      = (float*)         take(4194304);
    float*          logitsb = (float*)         take(1048576);
    unsigned short* attb    = (unsigned short*)take(524288);
    float2*         parts   = (float2*)        take(4096000);
    float*          tgt     = (float*)         take(8192);
    unsigned short* fcWb    = (unsigned short*)take(65536000);
    size_t need = off;
    (void)in_sizes; (void)n_in;

    if (ws_size < need) {
        // Not enough scratch: fail visibly (absmax error) instead of faulting.
        hipLaunchKernelGGL(zero_out_kernel, dim3((out_size + 63) / 64), dim3(64),
                           0, stream, (float*)d_out, out_size);
        return;
    }

    hipLaunchKernelGGL(prep_kernel, dim3(30784), dim3(256), 0, stream,
                       X, enc, emb, Wih0, Whh0, Wih1, Whh1, attnW, h0,
                       wih0b, whh0b, wih1b, whh1b, whb, web, encb, enctb,
                       xsb, h0buf, h1buf, ctrl);
    hipLaunchKernelGGL(a0_kernel, dim3(32, 32), dim3(256), 0, stream,
                       xsb, wih0b, bih0, bhh0, A0b);
    hipLaunchKernelGGL(lstm_kernel, dim3(256), dim3(512), 0, stream,
                       A0b, whh0b, wih1b, whh1b, bih1, bhh1, c0,
                       h0buf, h1buf, hallb, gmat, ctrl, fcW, fcWb,
                       encb, web, attnb, pe);
    hipLaunchKernelGGL(phpe_kernel, dim3(32, 8, 1), dim3(256), 0, stream,
                       hallb, encb, whb, web, attnb, ph, pe);
    hipLaunchKernelGGL(logits_kernel, dim3(2048), dim3(256), 0, stream,
                       ph, pe, vw, logitsb);
    hipLaunchKernelGGL(att_kernel, dim3(128), dim3(128), 0, stream,
                       logitsb, attb);
    hipLaunchKernelGGL(weighted_kernel, dim3(2, 8, 16), dim3(256), 0, stream,
                       attb, enctb, gmat);
    hipLaunchKernelGGL(fc_kernel, dim3(4512), dim3(256), 0, stream,
                       gmat, fcWb, fcb, parts, X, fcW, tgt);
    hipLaunchKernelGGL(row_lse_kernel, dim3(256), dim3(256), 0, stream,
                       parts, tgt, X, (float*)d_out, ctrl + 2048);
}